// Round 10
// baseline (105.793 us; speedup 1.0000x reference)
//
#include <hip/hip_runtime.h>

typedef int   i32x4v __attribute__((ext_vector_type(4)));
typedef int   i32x8v __attribute__((ext_vector_type(8)));
typedef float f32x16 __attribute__((ext_vector_type(16)));

#define GLOBAL_AS(p) ((const __attribute__((address_space(1))) void*)(p))
#define LDS_AS(p)    ((__attribute__((address_space(3))) void*)(p))
#define BAR()     __builtin_amdgcn_s_barrier()
#define VMCNT(n)  asm volatile("s_waitcnt vmcnt(" #n ")" ::: "memory")

// e2m1 RTN code (values {0,.5,1,1.5,2,3,4,6}; code == bit pattern, sign=0)
__device__ inline int fp4_code(float v) {
  return (v > 0.25f) + (v > 0.75f) + (v > 1.25f) + (v > 1.75f) +
         (v > 2.5f) + (v > 3.5f) + (v > 5.0f);
}

// ---- exp(x) -> fp4 e2m1 nibble-packed [M][K/2] + E8M0 scales SAt[K/32][M] ----
// one thread per (row m, 32-elem K-block kb)
__global__ void expcvt_a4_kernel(const float* __restrict__ x,
                                 unsigned char* __restrict__ A4,
                                 unsigned char* __restrict__ SAt,
                                 int M, int K) {
  const int NKB = K >> 5;
  const int t = blockIdx.x * blockDim.x + threadIdx.x;
  const int m = t / NKB, kb = t - m * NKB;
  if (m >= M) return;
  const float4* xs4 = (const float4*)(x + (size_t)m * K + kb * 32);
  float a[32];
  float bm = -3.0e38f;
#pragma unroll
  for (int j = 0; j < 8; ++j) {
    float4 v = xs4[j];
    a[4 * j] = v.x; a[4 * j + 1] = v.y; a[4 * j + 2] = v.z; a[4 * j + 3] = v.w;
    bm = fmaxf(bm, fmaxf(fmaxf(v.x, v.y), fmaxf(v.z, v.w)));
  }
  // scale exponent: exp(bm)/6 <= 2^e  ->  e = ceil(bm*log2(e) - log2(6))
  int e = (int)ceilf(bm * 1.44269504f - 2.58496250f);
  e = min(127, max(-126, e));
  SAt[(size_t)kb * M + m] = (unsigned char)(e + 127);
  uint4 u;
  unsigned d[4];
#pragma unroll
  for (int g = 0; g < 4; ++g) {
    unsigned acc = 0;
#pragma unroll
    for (int j = 0; j < 8; ++j) {
      float v = exp2f(a[g * 8 + j] * 1.44269504f - (float)e);
      acc |= (unsigned)fp4_code(v) << (4 * j);
    }
    d[g] = acc;
  }
  u.x = d[0]; u.y = d[1]; u.z = d[2]; u.w = d[3];
  *(uint4*)(A4 + (size_t)m * (K >> 1) + kb * 16) = u;
}

// ---- exp(w) -> fp4, transposed Bt4[n][K/2] + scales SBt[K/32][N] ----
__global__ void expcvt_wt4_kernel(const float* __restrict__ w,
                                  unsigned char* __restrict__ Bt4,
                                  unsigned char* __restrict__ SBt,
                                  int D, int O) {
  __shared__ float tile[32][33];
  int c0 = blockIdx.x * 32;   // O (col of w -> n)
  int r0 = blockIdx.y * 32;   // D (row of w -> k); one tile = one 32-K block
  int tx = threadIdx.x;       // 0..31
  int ty = threadIdx.y;       // 0..7
#pragma unroll
  for (int j = 0; j < 4; ++j) {
    int r = r0 + ty + j * 8;
    tile[ty + j * 8][tx] = __expf(w[(size_t)r * O + c0 + tx]);
  }
  __syncthreads();
  if (ty == 0) {
    const int n = tx;
    float bm = 0.0f;
#pragma unroll
    for (int d = 0; d < 32; ++d) bm = fmaxf(bm, tile[d][n]);
    int e = (int)ceilf(__log2f(bm) - 2.58496250f);
    e = min(127, max(-126, e));
    SBt[(size_t)(r0 >> 5) * O + c0 + n] = (unsigned char)(e + 127);
    const float inv = exp2f(-(float)e);
    uint4 u;
    unsigned d4[4];
#pragma unroll
    for (int g = 0; g < 4; ++g) {
      unsigned acc = 0;
#pragma unroll
      for (int j = 0; j < 8; ++j)
        acc |= (unsigned)fp4_code(tile[g * 8 + j][n] * inv) << (4 * j);
      d4[g] = acc;
    }
    u.x = d4[0]; u.y = d4[1]; u.z = d4[2]; u.w = d4[3];
    *(uint4*)(Bt4 + (size_t)(c0 + n) * (D >> 1) + (r0 >> 1)) = u;
  }
}

// ------- 128x256 3-buffer MX-fp4 MFMA GEMM (counted vmcnt), log+bias epilogue -------
// A4 : [M][K/2] fp4    Bt4 : [N][K/2] fp4    SAt/SBt : [K/32][M or N] E8M0
// out: [M][N] f32 = log(A@B) + bias[n]
// 256 thr = 4 waves (1 Mrow x 4 Ncol); wave C-tile 128x64 = 4mb x 2nb of 32x32x64.
// K-step = 64 elems = 32 B rows. LDS buffer (13312 B): A 4KB @0, B 8KB @4096,
// scales 1KB @12288 (SA[2][128] @+0, SB[2][256] @+256, dummy pad @+768); x3 bufs.
// Per wave per step exactly 4 global_load_lds (A 1 + B 2 + scale-role 1) ->
// uniform vmcnt ledger: stage t+2 each iter, VMCNT(4) retires t+1, barrier.
// Swizzle sigma_b(row)=((row>>2)^(row>>4))&1 on the 16B granule (<=2-way, free);
// applied on pre-swizzled global source AND on ds_read col. Frag = 1 ds_read_b128.

#define MFMA4(MB, NB)                                                        \
  acc[MB][NB] = __builtin_amdgcn_mfma_scale_f32_32x32x64_f8f6f4(             \
      a8[MB], b8[NB], acc[MB][NB], 4, 4, 0, sA[MB], 0, sB[NB]);

__global__ __launch_bounds__(256, 2) void gemm_mx4_kernel(
    const unsigned char* __restrict__ A4, const unsigned char* __restrict__ Bt4,
    const unsigned char* __restrict__ SAt, const unsigned char* __restrict__ SBt,
    const float* __restrict__ bias, float* __restrict__ out,
    int M, int N, int K) {
  __shared__ char lds[39936];          // 3 x 13312

  const int tid = threadIdx.x;
  const int wid = tid >> 6, lane = tid & 63;
  const int l31 = lane & 31, lk = lane >> 5;
  const int NTK = K >> 6;              // 64-elem K-steps (32)
  const size_t Kb = (size_t)K >> 1;    // bytes per fp4 row (1024)

  // XCD-aware bijective swizzle (gridDim.x % 8 == 0 here: 1024)
  const int cpx = gridDim.x >> 3;
  const int v   = (blockIdx.x & 7) * cpx + (blockIdx.x >> 3);
  const int nbn = N >> 8;
  const int bm  = v / nbn, bn = v % nbn;
  const int brow = bm << 7, bcol = bn << 8;

  // fragment read col offset: logical col16 = lk, physical = lk ^ sigma_b
  const int sbl = ((l31 >> 2) ^ (l31 >> 4)) & 1;
  const int c0x = ((lk ^ sbl) << 4);

  // hoisted staging sources (data koff = t*32 bytes added per step)
  const char* gA;
  {
    const int o = tid * 16, row = o >> 5;
    const int sbr = ((row >> 2) ^ (row >> 4)) & 1;
    gA = (const char*)A4 + (size_t)(brow + row) * Kb + ((o & 31) ^ (sbr << 4));
  }
  const char* gB[2];
#pragma unroll
  for (int i = 0; i < 2; ++i) {
    const int o = i * 4096 + tid * 16, row = o >> 5;
    const int sbr = ((row >> 2) ^ (row >> 4)) & 1;
    gB[i] = (const char*)Bt4 + (size_t)(bcol + row) * Kb + ((o & 31) ^ (sbr << 4));
  }
  // per-wave scale role: wid0 -> SA (2x128B runs), wid1/2 -> SB kb0/kb1,
  // wid3 -> dummy dup of SA into pad (keeps 4 loads/wave/step uniform)
  const char* gS;
  size_t sstep;
  int sdst;
  if (wid == 1)      { gS = (const char*)SBt + bcol + lane * 4;            sstep = 2 * (size_t)N; sdst = 12544; }
  else if (wid == 2) { gS = (const char*)SBt + N + bcol + lane * 4;        sstep = 2 * (size_t)N; sdst = 12800; }
  else {
    gS = (const char*)SAt + ((lane >> 5) ? (size_t)M : 0) + brow + (lane & 31) * 4;
    sstep = 2 * (size_t)M;
    sdst = (wid == 0) ? 12288 : 13056;
  }

  auto STAGE = [&](int t, int s) {
    const int tt = (t < NTK) ? t : NTK - 1;    // clamp keeps ledger uniform
    char* base = lds + s * 13312;
    __builtin_amdgcn_global_load_lds(GLOBAL_AS(gA + tt * 32),
        LDS_AS(base + tid * 16), 16, 0, 0);
#pragma unroll
    for (int i = 0; i < 2; ++i)
      __builtin_amdgcn_global_load_lds(GLOBAL_AS(gB[i] + tt * 32),
          LDS_AS(base + 4096 + i * 4096 + tid * 16), 16, 0, 0);
    __builtin_amdgcn_global_load_lds(GLOBAL_AS(gS + (size_t)tt * sstep),
        LDS_AS(base + sdst + lane * 4), 4, 0, 0);
  };

  f32x16 acc[4][2];
#pragma unroll
  for (int m = 0; m < 4; ++m)
#pragma unroll
    for (int n = 0; n < 2; ++n) acc[m][n] = (f32x16)0.0f;

  STAGE(0, 0);
  STAGE(1, 1);
  VMCNT(4);
  BAR();

  int s0 = 0, s1 = 1, s2 = 2;
  for (int t = 0; t < NTK; ++t) {
    STAGE(t + 2, s2);

    const char* bufb = lds + s0 * 13312;
    i32x8v a8[4], b8[2];
    int sA[4], sB[2];
#pragma unroll
    for (int mb = 0; mb < 4; ++mb) {
      i32x4v f = *(const i32x4v*)(bufb + mb * 1024 + l31 * 32 + c0x);
      a8[mb] = __builtin_shufflevector(f, f, 0, 1, 2, 3, -1, -1, -1, -1);
      sA[mb] = *(const unsigned char*)(bufb + 12288 + lk * 128 + mb * 32 + l31);
    }
#pragma unroll
    for (int nb = 0; nb < 2; ++nb) {
      i32x4v f = *(const i32x4v*)(bufb + 4096 + wid * 2048 + nb * 1024 +
                                  l31 * 32 + c0x);
      b8[nb] = __builtin_shufflevector(f, f, 0, 1, 2, 3, -1, -1, -1, -1);
      sB[nb] = *(const unsigned char*)(bufb + 12544 + lk * 256 + wid * 64 +
                                       nb * 32 + l31);
    }
    MFMA4(0, 0) MFMA4(1, 0) MFMA4(2, 0) MFMA4(3, 0)
    MFMA4(0, 1) MFMA4(1, 1) MFMA4(2, 1) MFMA4(3, 1)

    VMCNT(4);   // retire buf[t+1]'s 4 own loads; buf[t+2]'s stay in flight
    BAR();
    const int sw = s0; s0 = s1; s1 = s2; s2 = sw;
  }

  // epilogue: out = log(acc) + bias, nontemporal
  // 32x32 C/D layout: col = lane&31, row = (reg&3) + 8*(reg>>2) + 4*(lane>>5)
  const int col0 = bcol + wid * 64 + l31;
  const int row0 = brow + lk * 4;
  const float bv0 = bias[col0], bv1 = bias[col0 + 32];
#pragma unroll
  for (int mb = 0; mb < 4; ++mb) {
#pragma unroll
    for (int rg = 0; rg < 16; ++rg) {
      const int row = row0 + mb * 32 + (rg & 3) + 8 * (rg >> 2);
      const size_t ro = (size_t)row * N + col0;
      __builtin_nontemporal_store(__logf(acc[mb][0][rg]) + bv0, &out[ro]);
      __builtin_nontemporal_store(__logf(acc[mb][1][rg]) + bv1, &out[ro + 32]);
    }
  }
}

extern "C" void kernel_launch(void* const* d_in, const int* in_sizes, int n_in,
                              void* d_out, int out_size, void* d_ws, size_t ws_size,
                              hipStream_t stream) {
  const float* inputs = (const float*)d_in[0];
  const float* w      = (const float*)d_in[1];
  const float* bias   = (const float*)d_in[2];
  float* out = (float*)d_out;

  const int O = in_sizes[2];                 // 2048
  const int D = in_sizes[1] / O;             // 2048
  const size_t MD = (size_t)in_sizes[0];     // M*D
  const int M = (int)(MD / (size_t)D);       // 16384

  unsigned char* ws  = (unsigned char*)d_ws;
  unsigned char* A4  = ws;                                   // 16 MB
  unsigned char* Bt4 = ws + MD / 2;                          // 2 MB
  unsigned char* SAt = Bt4 + (size_t)O * D / 2;              // 1 MB
  unsigned char* SBt = SAt + MD / 32;                        // 128 KB

  const int nthr = (int)((MD / 32 + 255) / 256);
  expcvt_a4_kernel<<<nthr, 256, 0, stream>>>(inputs, A4, SAt, M, D);

  dim3 tg(O / 32, D / 32);
  expcvt_wt4_kernel<<<tg, dim3(32, 8), 0, stream>>>(w, Bt4, SBt, D, O);

  dim3 grid((M / 128) * (O / 256));
  gemm_mx4_kernel<<<grid, 256, 0, stream>>>(A4, Bt4, SAt, SBt, bias, out,
                                            M, O, D);
}

// Round 11
// 103.526 us; speedup vs baseline: 1.0219x; 1.0219x over previous
//
#include <hip/hip_runtime.h>

typedef int   i32x4v __attribute__((ext_vector_type(4)));
typedef int   i32x8v __attribute__((ext_vector_type(8)));
typedef float f32x16 __attribute__((ext_vector_type(16)));

#define GLOBAL_AS(p) ((const __attribute__((address_space(1))) void*)(p))
#define LDS_AS(p)    ((__attribute__((address_space(3))) void*)(p))
#define BAR()     __builtin_amdgcn_s_barrier()
#define VMCNT(n)  asm volatile("s_waitcnt vmcnt(" #n ")" ::: "memory")

// e2m1 RTN code (values {0,.5,1,1.5,2,3,4,6}; code == bit pattern, sign=0)
__device__ inline int fp4_code(float v) {
  return (v > 0.25f) + (v > 0.75f) + (v > 1.25f) + (v > 1.75f) +
         (v > 2.5f) + (v > 3.5f) + (v > 5.0f);
}

// ---- exp(x) -> fp4 e2m1 nibble-packed [M][K/2] + E8M0 scales (packed layout) ----
// SAt packed: addr = kb*M + (m>>7)*128 + (m&31)*4 + ((m>>5)&3)
// one thread per (row m, 32-elem K-block kb)
__global__ void expcvt_a4_kernel(const float* __restrict__ x,
                                 unsigned char* __restrict__ A4,
                                 unsigned char* __restrict__ SAt,
                                 int M, int K) {
  const int NKB = K >> 5;
  const int t = blockIdx.x * blockDim.x + threadIdx.x;
  const int m = t / NKB, kb = t - m * NKB;
  if (m >= M) return;
  const float4* xs4 = (const float4*)(x + (size_t)m * K + kb * 32);
  float a[32];
  float bm = -3.0e38f;
#pragma unroll
  for (int j = 0; j < 8; ++j) {
    float4 v = xs4[j];
    a[4 * j] = v.x; a[4 * j + 1] = v.y; a[4 * j + 2] = v.z; a[4 * j + 3] = v.w;
    bm = fmaxf(bm, fmaxf(fmaxf(v.x, v.y), fmaxf(v.z, v.w)));
  }
  int e = (int)ceilf(bm * 1.44269504f - 2.58496250f);
  e = min(127, max(-126, e));
  SAt[(size_t)kb * M + ((m >> 7) << 7) + ((m & 31) << 2) + ((m >> 5) & 3)] =
      (unsigned char)(e + 127);
  uint4 u;
  unsigned d[4];
#pragma unroll
  for (int g = 0; g < 4; ++g) {
    unsigned acc = 0;
#pragma unroll
    for (int j = 0; j < 8; ++j) {
      float v = exp2f(a[g * 8 + j] * 1.44269504f - (float)e);
      acc |= (unsigned)fp4_code(v) << (4 * j);
    }
    d[g] = acc;
  }
  u.x = d[0]; u.y = d[1]; u.z = d[2]; u.w = d[3];
  *(uint4*)(A4 + (size_t)m * (K >> 1) + kb * 16) = u;
}

// ---- exp(w) -> fp4, transposed Bt4[n][K/2] + packed scales ----
// SBt packed: addr = kb*O + (n>>8)*256 + (n&31)*8 + ((n>>5)&7)
__global__ void expcvt_wt4_kernel(const float* __restrict__ w,
                                  unsigned char* __restrict__ Bt4,
                                  unsigned char* __restrict__ SBt,
                                  int D, int O) {
  __shared__ float tile[32][33];
  int c0 = blockIdx.x * 32;   // O (col of w -> n)
  int r0 = blockIdx.y * 32;   // D (row of w -> k); one tile = one 32-K block
  int tx = threadIdx.x;       // 0..31
  int ty = threadIdx.y;       // 0..7
#pragma unroll
  for (int j = 0; j < 4; ++j) {
    int r = r0 + ty + j * 8;
    tile[ty + j * 8][tx] = __expf(w[(size_t)r * O + c0 + tx]);
  }
  __syncthreads();
  if (ty == 0) {
    const int n = c0 + tx;
    float bm = 0.0f;
#pragma unroll
    for (int d = 0; d < 32; ++d) bm = fmaxf(bm, tile[d][tx]);
    int e = (int)ceilf(__log2f(bm) - 2.58496250f);
    e = min(127, max(-126, e));
    SBt[(size_t)(r0 >> 5) * O + ((n >> 8) << 8) + ((n & 31) << 3) +
        ((n >> 5) & 7)] = (unsigned char)(e + 127);
    const float inv = exp2f(-(float)e);
    uint4 u;
    unsigned d4[4];
#pragma unroll
    for (int g = 0; g < 4; ++g) {
      unsigned acc = 0;
#pragma unroll
      for (int j = 0; j < 8; ++j)
        acc |= (unsigned)fp4_code(tile[g * 8 + j][tx] * inv) << (4 * j);
      d4[g] = acc;
    }
    u.x = d4[0]; u.y = d4[1]; u.z = d4[2]; u.w = d4[3];
    *(uint4*)(Bt4 + (size_t)n * (D >> 1) + (r0 >> 1)) = u;
  }
}

// --- 128x256 3-buffer MX-fp4 GEMM, K-step 128, packed scales, log+bias epilogue ---
// 256 thr = 4 waves (1 Mrow x 4 Ncol); wave C 128x64 = 4mb x 2nb; 16 MFMA/iter
// (2 k-halves h). Buffer 26624B: A 8KB @0, B 16KB @8192, SA 512B @24576,
// SB 1KB @25088, pad 512B @26112; x3 = 79872 (2 blocks/CU).
// Data rows 64B; LDS granule order [lk][h] via source granule-swap so the
// proven sigma_q XOR gives quad-distinct banks. vmcnt(8) counted ledger.

#define MFMA4(MB, NB, AV, BV, SAv, SBv)                                      \
  acc[MB][NB] = __builtin_amdgcn_mfma_scale_f32_32x32x64_f8f6f4(             \
      AV, BV, acc[MB][NB], 4, 4, 0, SAv, 0, SBv);

__global__ __launch_bounds__(256, 2) void gemm_mx4b_kernel(
    const unsigned char* __restrict__ A4, const unsigned char* __restrict__ Bt4,
    const unsigned char* __restrict__ SAt, const unsigned char* __restrict__ SBt,
    const float* __restrict__ bias, float* __restrict__ out,
    int M, int N, int K) {
  __shared__ char lds[79872];          // 3 x 26624

  const int tid = threadIdx.x;
  const int wid = tid >> 6, lane = tid & 63;
  const int l31 = lane & 31, lk = lane >> 5;
  const int NTK = K >> 7;              // 128-elem K-steps (16)
  const size_t Kb = (size_t)K >> 1;    // bytes per fp4 row (1024)

  // XCD-aware bijective swizzle (gridDim.x % 8 == 0 here: 1024)
  const int cpx = gridDim.x >> 3;
  const int v   = (blockIdx.x & 7) * cpx + (blockIdx.x >> 3);
  const int nbn = N >> 8;
  const int bm  = v / nbn, bn = v % nbn;
  const int brow = bm << 7, bcol = bn << 8;

  // read offsets: logical granule gl = lk*2 + h at bit4..5, XOR sigma_q(l31)
  const int swz = ((l31 & 6) << 3) ^ (l31 & 16);
  const int cR0 = (lk << 5) ^ swz;     // h=0 ; h=1 -> cR0 ^ 16

  // staging sources: granule-swapped + inverse-swizzled (koff = tt*64 added)
  const char* gA[2];
  const char* gB[4];
#pragma unroll
  for (int i = 0; i < 2; ++i) {
    const int o = i * 4096 + tid * 16, row = o >> 6;
    const int sg = (((row & 6) << 3) ^ (row & 16)) >> 4;   // 2-bit granule swz
    const int gl = ((o >> 4) & 3) ^ sg;
    const int gs = ((gl & 1) << 1) | (gl >> 1);            // [lk][h] -> [h][lk]
    gA[i] = (const char*)A4 + (size_t)(brow + row) * Kb + (gs << 4) + (o & 15);
  }
#pragma unroll
  for (int i = 0; i < 4; ++i) {
    const int o = i * 4096 + tid * 16, row = o >> 6;
    const int sg = (((row & 6) << 3) ^ (row & 16)) >> 4;
    const int gl = ((o >> 4) & 3) ^ sg;
    const int gs = ((gl & 1) << 1) | (gl >> 1);
    gB[i] = (const char*)Bt4 + (size_t)(bcol + row) * Kb + (gs << 4) + (o & 15);
  }
  // scale sources (per-lane bases; + step*M / step*N per iter)
  const char* gSA = (const char*)SAt + (size_t)lk * M + brow + l31 * 4;
  const char* gSB = (const char*)SBt + bcol + (lane >> 1) * 8 + (lane & 1) * 4;

  auto STAGE = [&](int t, char* base) {
    const int tt = (t < NTK) ? t : NTK - 1;
    const int koff = tt << 6;
#pragma unroll
    for (int i = 0; i < 2; ++i)
      __builtin_amdgcn_global_load_lds(GLOBAL_AS(gA[i] + koff),
          LDS_AS(base + i * 4096 + wid * 1024), 16, 0, 0);
#pragma unroll
    for (int i = 0; i < 4; ++i)
      __builtin_amdgcn_global_load_lds(GLOBAL_AS(gB[i] + koff),
          LDS_AS(base + 8192 + i * 4096 + wid * 1024), 16, 0, 0);
    const size_t t4 = (size_t)(tt << 2);
    if (wid == 0) {
      __builtin_amdgcn_global_load_lds(GLOBAL_AS(gSA + t4 * M),
          LDS_AS(base + 24576), 4, 0, 0);
      __builtin_amdgcn_global_load_lds(GLOBAL_AS(gSA + t4 * M),
          LDS_AS(base + 26112), 4, 0, 0);                  // dummy (ledger)
    } else if (wid == 1) {
      __builtin_amdgcn_global_load_lds(GLOBAL_AS(gSA + (t4 + 2) * M),
          LDS_AS(base + 24832), 4, 0, 0);
      __builtin_amdgcn_global_load_lds(GLOBAL_AS(gSA + (t4 + 2) * M),
          LDS_AS(base + 26368), 4, 0, 0);                  // dummy
    } else if (wid == 2) {
      __builtin_amdgcn_global_load_lds(GLOBAL_AS(gSB + t4 * N),
          LDS_AS(base + 25088), 4, 0, 0);
      __builtin_amdgcn_global_load_lds(GLOBAL_AS(gSB + (t4 + 1) * N),
          LDS_AS(base + 25344), 4, 0, 0);
    } else {
      __builtin_amdgcn_global_load_lds(GLOBAL_AS(gSB + (t4 + 2) * N),
          LDS_AS(base + 25600), 4, 0, 0);
      __builtin_amdgcn_global_load_lds(GLOBAL_AS(gSB + (t4 + 3) * N),
          LDS_AS(base + 25856), 4, 0, 0);
    }
  };

  f32x16 acc[4][2];
#pragma unroll
  for (int m = 0; m < 4; ++m)
#pragma unroll
    for (int n = 0; n < 2; ++n) acc[m][n] = (f32x16)0.0f;

  char* L0 = lds;
  char* L1 = lds + 26624;
  char* L2 = lds + 53248;

  STAGE(0, L0);
  STAGE(1, L1);
  VMCNT(8);
  BAR();

  const int shB = (wid & 1) << 4;      // SB byte-shift base (runtime, uniform)

  for (int t = 0; t < NTK; ++t) {
    STAGE(t + 2, L2);

    const char* bA = L0;
    const char* bB = L0 + 8192;
#pragma unroll
    for (int h = 0; h < 2; ++h) {
      const int ch = cR0 ^ (h << 4);
      i32x8v a8[4], b8[2];
#pragma unroll
      for (int mb = 0; mb < 4; ++mb) {
        i32x4v f = *(const i32x4v*)(bA + (mb * 32 + l31) * 64 + ch);
        a8[mb] = __builtin_shufflevector(f, f, 0, 1, 2, 3, -1, -1, -1, -1);
      }
#pragma unroll
      for (int nb = 0; nb < 2; ++nb) {
        i32x4v f = *(const i32x4v*)(bB + (wid * 64 + nb * 32 + l31) * 64 + ch);
        b8[nb] = __builtin_shufflevector(f, f, 0, 1, 2, 3, -1, -1, -1, -1);
      }
      const int kb2 = 2 * h + lk;
      const int sAw = *(const int*)(L0 + 24576 + (kb2 * 32 + l31) * 4);
      const int2 sBd = *(const int2*)(L0 + 25088 + kb2 * 256 + l31 * 8);
      const int sel = (wid < 2) ? sBd.x : sBd.y;
      const int sB0 = (sel >> shB) & 0xFF;
      const int sB1 = (sel >> (shB + 8)) & 0xFF;
      const int sA0 = sAw & 0xFF, sA1 = (sAw >> 8) & 0xFF;
      const int sA2 = (sAw >> 16) & 0xFF, sA3 = (sAw >> 24) & 0xFF;
      MFMA4(0, 0, a8[0], b8[0], sA0, sB0) MFMA4(1, 0, a8[1], b8[0], sA1, sB0)
      MFMA4(2, 0, a8[2], b8[0], sA2, sB0) MFMA4(3, 0, a8[3], b8[0], sA3, sB0)
      MFMA4(0, 1, a8[0], b8[1], sA0, sB1) MFMA4(1, 1, a8[1], b8[1], sA1, sB1)
      MFMA4(2, 1, a8[2], b8[1], sA2, sB1) MFMA4(3, 1, a8[3], b8[1], sA3, sB1)
    }

    VMCNT(8);   // retire buf[t+1]'s 8 loads; buf[t+2]'s 8 stay in flight
    BAR();
    char* sw = L0; L0 = L1; L1 = L2; L2 = sw;
  }

  VMCNT(0);

  // epilogue: out = log(acc) + bias, nontemporal
  // 32x32 C/D layout: col = lane&31, row = (reg&3) + 8*(reg>>2) + 4*(lane>>5)
  const int col0 = bcol + wid * 64 + l31;
  const int row0 = brow + lk * 4;
  const float bv0 = bias[col0], bv1 = bias[col0 + 32];
#pragma unroll
  for (int mb = 0; mb < 4; ++mb) {
#pragma unroll
    for (int rg = 0; rg < 16; ++rg) {
      const int row = row0 + mb * 32 + (rg & 3) + 8 * (rg >> 2);
      const size_t ro = (size_t)row * N + col0;
      __builtin_nontemporal_store(__logf(acc[mb][0][rg]) + bv0, &out[ro]);
      __builtin_nontemporal_store(__logf(acc[mb][1][rg]) + bv1, &out[ro + 32]);
    }
  }
}

extern "C" void kernel_launch(void* const* d_in, const int* in_sizes, int n_in,
                              void* d_out, int out_size, void* d_ws, size_t ws_size,
                              hipStream_t stream) {
  const float* inputs = (const float*)d_in[0];
  const float* w      = (const float*)d_in[1];
  const float* bias   = (const float*)d_in[2];
  float* out = (float*)d_out;

  const int O = in_sizes[2];                 // 2048
  const int D = in_sizes[1] / O;             // 2048
  const size_t MD = (size_t)in_sizes[0];     // M*D
  const int M = (int)(MD / (size_t)D);       // 16384

  unsigned char* ws  = (unsigned char*)d_ws;
  unsigned char* A4  = ws;                                   // 16 MB
  unsigned char* Bt4 = ws + MD / 2;                          // 2 MB
  unsigned char* SAt = Bt4 + (size_t)O * D / 2;              // 1 MB
  unsigned char* SBt = SAt + MD / 32;                        // 128 KB

  const int nthr = (int)((MD / 32 + 255) / 256);
  expcvt_a4_kernel<<<nthr, 256, 0, stream>>>(inputs, A4, SAt, M, D);

  dim3 tg(O / 32, D / 32);
  expcvt_wt4_kernel<<<tg, dim3(32, 8), 0, stream>>>(w, Bt4, SBt, D, O);

  dim3 grid((M / 128) * (O / 256));
  gemm_mx4b_kernel<<<grid, 256, 0, stream>>>(A4, Bt4, SAt, SBt, bias, out,
                                             M, O, D);
}

// Round 12
// 90.466 us; speedup vs baseline: 1.1694x; 1.1444x over previous
//
#include <hip/hip_runtime.h>

typedef int   i32x4v __attribute__((ext_vector_type(4)));
typedef int   i32x8v __attribute__((ext_vector_type(8)));
typedef float f32x16 __attribute__((ext_vector_type(16)));

#define GLOBAL_AS(p) ((const __attribute__((address_space(1))) void*)(p))
#define LDS_AS(p)    ((__attribute__((address_space(3))) void*)(p))
#define BAR()     __builtin_amdgcn_s_barrier()
#define VMCNT(n)  asm volatile("s_waitcnt vmcnt(" #n ")" ::: "memory")

// e2m1 RTN code (values {0,.5,1,1.5,2,3,4,6}; code == bit pattern, sign=0)
__device__ inline int fp4_code(float v) {
  return (v > 0.25f) + (v > 0.75f) + (v > 1.25f) + (v > 1.75f) +
         (v > 2.5f) + (v > 3.5f) + (v > 5.0f);
}

// ---- exp(x) -> fp4 e2m1 nibble-packed [M][K/2] + E8M0 scales (packed layout) ----
// SAt packed: addr = kb*M + (m>>7)*128 + (m&31)*4 + ((m>>5)&3)
__global__ void expcvt_a4_kernel(const float* __restrict__ x,
                                 unsigned char* __restrict__ A4,
                                 unsigned char* __restrict__ SAt,
                                 int M, int K) {
  const int NKB = K >> 5;
  const int t = blockIdx.x * blockDim.x + threadIdx.x;
  const int m = t / NKB, kb = t - m * NKB;
  if (m >= M) return;
  const float4* xs4 = (const float4*)(x + (size_t)m * K + kb * 32);
  float a[32];
  float bm = -3.0e38f;
#pragma unroll
  for (int j = 0; j < 8; ++j) {
    float4 v = xs4[j];
    a[4 * j] = v.x; a[4 * j + 1] = v.y; a[4 * j + 2] = v.z; a[4 * j + 3] = v.w;
    bm = fmaxf(bm, fmaxf(fmaxf(v.x, v.y), fmaxf(v.z, v.w)));
  }
  int e = (int)ceilf(bm * 1.44269504f - 2.58496250f);
  e = min(127, max(-126, e));
  SAt[(size_t)kb * M + ((m >> 7) << 7) + ((m & 31) << 2) + ((m >> 5) & 3)] =
      (unsigned char)(e + 127);
  uint4 u;
  unsigned d[4];
#pragma unroll
  for (int g = 0; g < 4; ++g) {
    unsigned acc = 0;
#pragma unroll
    for (int j = 0; j < 8; ++j) {
      float v = exp2f(a[g * 8 + j] * 1.44269504f - (float)e);
      acc |= (unsigned)fp4_code(v) << (4 * j);
    }
    d[g] = acc;
  }
  u.x = d[0]; u.y = d[1]; u.z = d[2]; u.w = d[3];
  *(uint4*)(A4 + (size_t)m * (K >> 1) + kb * 16) = u;
}

// ---- exp(w) -> fp4, transposed Bt4[n][K/2] + packed scales ----
// SBt packed for 128-wide N blocks: addr = kb*O + (n>>7)*128 + (n&31)*4 + ((n>>5)&3)
__global__ void expcvt_wt4_kernel(const float* __restrict__ w,
                                  unsigned char* __restrict__ Bt4,
                                  unsigned char* __restrict__ SBt,
                                  int D, int O) {
  __shared__ float tile[32][33];
  int c0 = blockIdx.x * 32;   // O (col of w -> n)
  int r0 = blockIdx.y * 32;   // D (row of w -> k); one tile = one 32-K block
  int tx = threadIdx.x;       // 0..31
  int ty = threadIdx.y;       // 0..7
#pragma unroll
  for (int j = 0; j < 4; ++j) {
    int r = r0 + ty + j * 8;
    tile[ty + j * 8][tx] = __expf(w[(size_t)r * O + c0 + tx]);
  }
  __syncthreads();
  if (ty == 0) {
    const int n = c0 + tx;
    float bm = 0.0f;
#pragma unroll
    for (int d = 0; d < 32; ++d) bm = fmaxf(bm, tile[d][tx]);
    int e = (int)ceilf(__log2f(bm) - 2.58496250f);
    e = min(127, max(-126, e));
    SBt[(size_t)(r0 >> 5) * O + ((n >> 7) << 7) + ((n & 31) << 2) +
        ((n >> 5) & 3)] = (unsigned char)(e + 127);
    const float inv = exp2f(-(float)e);
    uint4 u;
    unsigned d4[4];
#pragma unroll
    for (int g = 0; g < 4; ++g) {
      unsigned acc = 0;
#pragma unroll
      for (int j = 0; j < 8; ++j)
        acc |= (unsigned)fp4_code(tile[g * 8 + j][tx] * inv) << (4 * j);
      d4[g] = acc;
    }
    u.x = d4[0]; u.y = d4[1]; u.z = d4[2]; u.w = d4[3];
    *(uint4*)(Bt4 + (size_t)n * (D >> 1) + (r0 >> 1)) = u;
  }
}

// --- 128x128 3-buffer MX-fp4 GEMM, 3 blocks/CU, K-step 128, log+bias epilogue ---
// 256 thr = 4 waves (2M x 2N); wave C-tile 64x64 = 2mb x 2nb of 32x32x64; acc 64
// VGPR -> ~130 regs/wave -> 3 waves/SIMD. Buffer 17408B: A 8KB @0, B 8KB @8192,
// SA 512B @16384, SB 512B @16896; x3 = 52224 -> 3 blocks/CU.
// 5 global_load_lds per wave per STAGE (2 A + 2 B + 1 scale) -> counted
// VMCNT(5): stage t+2, retire t+1, never drain. sigma_q granule swizzle (r11).

#define MFMA4(MB, NB, AV, BV, SAv, SBv)                                      \
  acc[MB][NB] = __builtin_amdgcn_mfma_scale_f32_32x32x64_f8f6f4(             \
      AV, BV, acc[MB][NB], 4, 4, 0, SAv, 0, SBv);

__global__ __launch_bounds__(256, 3) void gemm_mx4c_kernel(
    const unsigned char* __restrict__ A4, const unsigned char* __restrict__ Bt4,
    const unsigned char* __restrict__ SAt, const unsigned char* __restrict__ SBt,
    const float* __restrict__ bias, float* __restrict__ out,
    int M, int N, int K) {
  __shared__ char lds[52224];          // 3 x 17408

  const int tid = threadIdx.x;
  const int wid = tid >> 6, lane = tid & 63;
  const int wr = wid >> 1, wc = wid & 1;
  const int l31 = lane & 31, lk = lane >> 5;
  const int NTK = K >> 7;              // 128-elem K-steps (16)
  const size_t Kb = (size_t)K >> 1;    // bytes per fp4 row (1024)

  // XCD-aware bijective swizzle (gridDim.x % 8 == 0 here: 2048)
  const int cpx = gridDim.x >> 3;
  const int v   = (blockIdx.x & 7) * cpx + (blockIdx.x >> 3);
  const int nbn = N >> 7;
  const int bm  = v / nbn, bn = v % nbn;
  const int brow = bm << 7, bcol = bn << 7;

  // read offsets: logical granule gl = lk*2 + h at bits 4..5, XOR sigma_q(l31)
  const int swz = ((l31 & 6) << 3) ^ (l31 & 16);
  const int cR0 = (lk << 5) ^ swz;     // h=0 ; h=1 -> cR0 ^ 16

  // staging sources: granule-swapped + inverse-swizzled (koff = tt*64 added)
  const char* gA[2];
  const char* gB[2];
#pragma unroll
  for (int i = 0; i < 2; ++i) {
    const int o = i * 4096 + tid * 16, row = o >> 6;
    const int sg = (((row & 6) << 3) ^ (row & 16)) >> 4;   // 2-bit granule swz
    const int gl = ((o >> 4) & 3) ^ sg;
    const int gs = ((gl & 1) << 1) | (gl >> 1);            // [lk][h] -> [h][lk]
    gA[i] = (const char*)A4 + (size_t)(brow + row) * Kb + (gs << 4);
    gB[i] = (const char*)Bt4 + (size_t)(bcol + row) * Kb + (gs << 4);
  }
  // scale source: waves 0/1 -> SA kb {0,1}/{2,3}; waves 2/3 -> SB kb {0,1}/{2,3}
  const char* gS;
  size_t sstep;
  if (wid < 2) {
    gS = (const char*)SAt + ((size_t)(lane >> 5) + 2 * wid) * M + brow + l31 * 4;
    sstep = 4 * (size_t)M;
  } else {
    gS = (const char*)SBt + ((size_t)(lane >> 5) + 2 * (wid - 2)) * N + bcol +
         l31 * 4;
    sstep = 4 * (size_t)N;
  }

  auto STAGE = [&](int t, char* base) {
    const int tt = (t < NTK) ? t : NTK - 1;    // clamp keeps ledger uniform
    const int koff = tt << 6;
#pragma unroll
    for (int i = 0; i < 2; ++i) {
      __builtin_amdgcn_global_load_lds(GLOBAL_AS(gA[i] + koff),
          LDS_AS(base + i * 4096 + wid * 1024), 16, 0, 0);
      __builtin_amdgcn_global_load_lds(GLOBAL_AS(gB[i] + koff),
          LDS_AS(base + 8192 + i * 4096 + wid * 1024), 16, 0, 0);
    }
    __builtin_amdgcn_global_load_lds(GLOBAL_AS(gS + (size_t)tt * sstep),
        LDS_AS(base + 16384 + wid * 256 + lane * 4), 4, 0, 0);
  };

  f32x16 acc[2][2];
#pragma unroll
  for (int m = 0; m < 2; ++m)
#pragma unroll
    for (int n = 0; n < 2; ++n) acc[m][n] = (f32x16)0.0f;

  char* L0 = lds;
  char* L1 = lds + 17408;
  char* L2 = lds + 34816;

  STAGE(0, L0);
  STAGE(1, L1);
  VMCNT(5);
  BAR();

  const int shA = wr << 4;     // byte (2wr+mb) -> shift shA + mb*8 (wave-uniform)
  const int shB = wc << 4;

  for (int t = 0; t < NTK; ++t) {
    STAGE(t + 2, L2);

    const char* bA = L0 + wr * 4096;
    const char* bB = L0 + 8192 + wc * 4096;
#pragma unroll
    for (int h = 0; h < 2; ++h) {
      const int ch = cR0 ^ (h << 4);
      i32x8v a8[2], b8[2];
#pragma unroll
      for (int mb = 0; mb < 2; ++mb) {
        i32x4v f = *(const i32x4v*)(bA + (mb * 32 + l31) * 64 + ch);
        a8[mb] = __builtin_shufflevector(f, f, 0, 1, 2, 3, -1, -1, -1, -1);
      }
#pragma unroll
      for (int nb = 0; nb < 2; ++nb) {
        i32x4v f = *(const i32x4v*)(bB + (nb * 32 + l31) * 64 + ch);
        b8[nb] = __builtin_shufflevector(f, f, 0, 1, 2, 3, -1, -1, -1, -1);
      }
      const int kb2 = 2 * h + lk;
      const int saw = *(const int*)(L0 + 16384 + kb2 * 128 + l31 * 4);
      const int sbw = *(const int*)(L0 + 16896 + kb2 * 128 + l31 * 4);
      const int sA0 = (saw >> shA) & 0xFF, sA1 = (saw >> (shA + 8)) & 0xFF;
      const int sB0 = (sbw >> shB) & 0xFF, sB1 = (sbw >> (shB + 8)) & 0xFF;
      MFMA4(0, 0, a8[0], b8[0], sA0, sB0)
      MFMA4(1, 0, a8[1], b8[0], sA1, sB0)
      MFMA4(0, 1, a8[0], b8[1], sA0, sB1)
      MFMA4(1, 1, a8[1], b8[1], sA1, sB1)
    }

    VMCNT(5);   // retire buf[t+1]'s 5 own loads; buf[t+2]'s 5 stay in flight
    BAR();
    char* sw = L0; L0 = L1; L1 = L2; L2 = sw;
  }

  // epilogue: out = log(acc) + bias, nontemporal
  // 32x32 C/D layout: col = lane&31, row = (reg&3) + 8*(reg>>2) + 4*(lane>>5)
  const int col0 = bcol + wc * 64 + l31;
  const int row0 = brow + wr * 64 + lk * 4;
  const float bv0 = bias[col0], bv1 = bias[col0 + 32];
#pragma unroll
  for (int mb = 0; mb < 2; ++mb) {
#pragma unroll
    for (int rg = 0; rg < 16; ++rg) {
      const int row = row0 + mb * 32 + (rg & 3) + 8 * (rg >> 2);
      const size_t ro = (size_t)row * N + col0;
      __builtin_nontemporal_store(__logf(acc[mb][0][rg]) + bv0, &out[ro]);
      __builtin_nontemporal_store(__logf(acc[mb][1][rg]) + bv1, &out[ro + 32]);
    }
  }
}

extern "C" void kernel_launch(void* const* d_in, const int* in_sizes, int n_in,
                              void* d_out, int out_size, void* d_ws, size_t ws_size,
                              hipStream_t stream) {
  const float* inputs = (const float*)d_in[0];
  const float* w      = (const float*)d_in[1];
  const float* bias   = (const float*)d_in[2];
  float* out = (float*)d_out;

  const int O = in_sizes[2];                 // 2048
  const int D = in_sizes[1] / O;             // 2048
  const size_t MD = (size_t)in_sizes[0];     // M*D
  const int M = (int)(MD / (size_t)D);       // 16384

  unsigned char* ws  = (unsigned char*)d_ws;
  unsigned char* A4  = ws;                                   // 16 MB
  unsigned char* Bt4 = ws + MD / 2;                          // 2 MB
  unsigned char* SAt = Bt4 + (size_t)O * D / 2;              // 1 MB
  unsigned char* SBt = SAt + MD / 32;                        // 128 KB

  const int nthr = (int)((MD / 32 + 255) / 256);
  expcvt_a4_kernel<<<nthr, 256, 0, stream>>>(inputs, A4, SAt, M, D);

  dim3 tg(O / 32, D / 32);
  expcvt_wt4_kernel<<<tg, dim3(32, 8), 0, stream>>>(w, Bt4, SBt, D, O);

  dim3 grid((M / 128) * (O / 128));
  gemm_mx4c_kernel<<<grid, 256, 0, stream>>>(A4, Bt4, SAt, SBt, bias, out,
                                             M, O, D);
}

// Round 13
// 88.785 us; speedup vs baseline: 1.1916x; 1.0189x over previous
//
#include <hip/hip_runtime.h>

typedef int   i32x4v __attribute__((ext_vector_type(4)));
typedef int   i32x8v __attribute__((ext_vector_type(8)));
typedef float f32x16 __attribute__((ext_vector_type(16)));

#define GLOBAL_AS(p) ((const __attribute__((address_space(1))) void*)(p))
#define LDS_AS(p)    ((__attribute__((address_space(3))) void*)(p))
#define BAR()     __builtin_amdgcn_s_barrier()
#define VMCNT(n)  asm volatile("s_waitcnt vmcnt(" #n ")" ::: "memory")

// e2m1 RTN code (values {0,.5,1,1.5,2,3,4,6}; code == bit pattern, sign=0)
__device__ inline int fp4_code(float v) {
  return (v > 0.25f) + (v > 0.75f) + (v > 1.25f) + (v > 1.75f) +
         (v > 2.5f) + (v > 3.5f) + (v > 5.0f);
}

// ---- exp(x) -> fp4 e2m1 nibble-packed [M][K/2] + E8M0 scales (packed layout) ----
// SAt packed: addr = kb*M + (m>>7)*128 + (m&31)*4 + ((m>>5)&3)
__global__ void expcvt_a4_kernel(const float* __restrict__ x,
                                 unsigned char* __restrict__ A4,
                                 unsigned char* __restrict__ SAt,
                                 int M, int K) {
  const int NKB = K >> 5;
  const int t = blockIdx.x * blockDim.x + threadIdx.x;
  const int m = t / NKB, kb = t - m * NKB;
  if (m >= M) return;
  const float4* xs4 = (const float4*)(x + (size_t)m * K + kb * 32);
  float a[32];
  float bm = -3.0e38f;
#pragma unroll
  for (int j = 0; j < 8; ++j) {
    float4 v = xs4[j];
    a[4 * j] = v.x; a[4 * j + 1] = v.y; a[4 * j + 2] = v.z; a[4 * j + 3] = v.w;
    bm = fmaxf(bm, fmaxf(fmaxf(v.x, v.y), fmaxf(v.z, v.w)));
  }
  int e = (int)ceilf(bm * 1.44269504f - 2.58496250f);
  e = min(127, max(-126, e));
  SAt[(size_t)kb * M + ((m >> 7) << 7) + ((m & 31) << 2) + ((m >> 5) & 3)] =
      (unsigned char)(e + 127);
  uint4 u;
  unsigned d[4];
#pragma unroll
  for (int g = 0; g < 4; ++g) {
    unsigned acc = 0;
#pragma unroll
    for (int j = 0; j < 8; ++j) {
      float v = exp2f(a[g * 8 + j] * 1.44269504f - (float)e);
      acc |= (unsigned)fp4_code(v) << (4 * j);
    }
    d[g] = acc;
  }
  u.x = d[0]; u.y = d[1]; u.z = d[2]; u.w = d[3];
  *(uint4*)(A4 + (size_t)m * (K >> 1) + kb * 16) = u;
}

// ---- exp(w) -> fp4, transposed Bt4[n][K/2] + packed scales ----
// SBt packed for 128-wide N blocks: addr = kb*O + (n>>7)*128 + (n&31)*4 + ((n>>5)&3)
__global__ void expcvt_wt4_kernel(const float* __restrict__ w,
                                  unsigned char* __restrict__ Bt4,
                                  unsigned char* __restrict__ SBt,
                                  int D, int O) {
  __shared__ float tile[32][33];
  int c0 = blockIdx.x * 32;   // O (col of w -> n)
  int r0 = blockIdx.y * 32;   // D (row of w -> k); one tile = one 32-K block
  int tx = threadIdx.x;       // 0..31
  int ty = threadIdx.y;       // 0..7
#pragma unroll
  for (int j = 0; j < 4; ++j) {
    int r = r0 + ty + j * 8;
    tile[ty + j * 8][tx] = __expf(w[(size_t)r * O + c0 + tx]);
  }
  __syncthreads();
  if (ty == 0) {
    const int n = c0 + tx;
    float bm = 0.0f;
#pragma unroll
    for (int d = 0; d < 32; ++d) bm = fmaxf(bm, tile[d][tx]);
    int e = (int)ceilf(__log2f(bm) - 2.58496250f);
    e = min(127, max(-126, e));
    SBt[(size_t)(r0 >> 5) * O + ((n >> 7) << 7) + ((n & 31) << 2) +
        ((n >> 5) & 3)] = (unsigned char)(e + 127);
    const float inv = exp2f(-(float)e);
    uint4 u;
    unsigned d4[4];
#pragma unroll
    for (int g = 0; g < 4; ++g) {
      unsigned acc = 0;
#pragma unroll
      for (int j = 0; j < 8; ++j)
        acc |= (unsigned)fp4_code(tile[g * 8 + j][tx] * inv) << (4 * j);
      d4[g] = acc;
    }
    u.x = d4[0]; u.y = d4[1]; u.z = d4[2]; u.w = d4[3];
    *(uint4*)(Bt4 + (size_t)n * (D >> 1) + (r0 >> 1)) = u;
  }
}

// --- 128x128 2-buffer MX-fp4 GEMM, 4 blocks/CU, K-step 128, log+bias epilogue ---
// 256 thr = 4 waves (2M x 2N); wave C-tile 64x64 = 2mb x 2nb of 32x32x64; acc 64
// VGPR -> ~100 regs/wave -> 4 waves/SIMD. Buffer 17408B: A 8KB @0, B 8KB @8192,
// SA 512B @16384, SB 512B @16896; x2 = 34816 -> 4 blocks/CU (16 waves).
// Classic double-buffer, stage distance 1 iter (~2500 cyc >> L2 latency):
// per iter { STAGE(t+1 -> other buf); VMCNT(5) retires t's loads; BAR;
//            ds_read + 16 MFMA from buf[t&1]; BAR }.  Loop unrolled x2 so
// buffer bases are compile-time. sigma_q granule swizzle (proven 0-conflict).

#define MFMA4(MB, NB, AV, BV, SAv, SBv)                                      \
  acc[MB][NB] = __builtin_amdgcn_mfma_scale_f32_32x32x64_f8f6f4(             \
      AV, BV, acc[MB][NB], 4, 4, 0, SAv, 0, SBv);

__global__ __launch_bounds__(256, 4) void gemm_mx4d_kernel(
    const unsigned char* __restrict__ A4, const unsigned char* __restrict__ Bt4,
    const unsigned char* __restrict__ SAt, const unsigned char* __restrict__ SBt,
    const float* __restrict__ bias, float* __restrict__ out,
    int M, int N, int K) {
  __shared__ char lds[34816];          // 2 x 17408

  const int tid = threadIdx.x;
  const int wid = tid >> 6, lane = tid & 63;
  const int wr = wid >> 1, wc = wid & 1;
  const int l31 = lane & 31, lk = lane >> 5;
  const int NTK = K >> 7;              // 128-elem K-steps (16)
  const size_t Kb = (size_t)K >> 1;    // bytes per fp4 row (1024)

  // XCD-aware bijective swizzle (gridDim.x % 8 == 0 here: 2048)
  const int cpx = gridDim.x >> 3;
  const int v   = (blockIdx.x & 7) * cpx + (blockIdx.x >> 3);
  const int nbn = N >> 7;
  const int bm  = v / nbn, bn = v % nbn;
  const int brow = bm << 7, bcol = bn << 7;

  // read offsets: logical granule gl = lk*2 + h at bits 4..5, XOR sigma_q(l31)
  const int swz = ((l31 & 6) << 3) ^ (l31 & 16);
  const int cR0 = (lk << 5) ^ swz;     // h=0 ; h=1 -> cR0 ^ 16

  // staging sources: granule-swapped + inverse-swizzled (koff = tt*64 added)
  const char* gA[2];
  const char* gB[2];
#pragma unroll
  for (int i = 0; i < 2; ++i) {
    const int o = i * 4096 + tid * 16, row = o >> 6;
    const int sg = (((row & 6) << 3) ^ (row & 16)) >> 4;   // 2-bit granule swz
    const int gl = ((o >> 4) & 3) ^ sg;
    const int gs = ((gl & 1) << 1) | (gl >> 1);            // [lk][h] -> [h][lk]
    gA[i] = (const char*)A4 + (size_t)(brow + row) * Kb + (gs << 4);
    gB[i] = (const char*)Bt4 + (size_t)(bcol + row) * Kb + (gs << 4);
  }
  // scale source: waves 0/1 -> SA kb {0,1}/{2,3}; waves 2/3 -> SB kb {0,1}/{2,3}
  const char* gS;
  size_t sstep;
  if (wid < 2) {
    gS = (const char*)SAt + ((size_t)(lane >> 5) + 2 * wid) * M + brow + l31 * 4;
    sstep = 4 * (size_t)M;
  } else {
    gS = (const char*)SBt + ((size_t)(lane >> 5) + 2 * (wid - 2)) * N + bcol +
         l31 * 4;
    sstep = 4 * (size_t)N;
  }

  auto STAGE = [&](int t, char* base) {
    const int tt = (t < NTK) ? t : NTK - 1;    // clamp keeps ledger uniform
    const int koff = tt << 6;
#pragma unroll
    for (int i = 0; i < 2; ++i) {
      __builtin_amdgcn_global_load_lds(GLOBAL_AS(gA[i] + koff),
          LDS_AS(base + i * 4096 + wid * 1024), 16, 0, 0);
      __builtin_amdgcn_global_load_lds(GLOBAL_AS(gB[i] + koff),
          LDS_AS(base + 8192 + i * 4096 + wid * 1024), 16, 0, 0);
    }
    __builtin_amdgcn_global_load_lds(GLOBAL_AS(gS + (size_t)tt * sstep),
        LDS_AS(base + 16384 + wid * 256 + lane * 4), 4, 0, 0);
  };

  f32x16 acc[2][2];
#pragma unroll
  for (int m = 0; m < 2; ++m)
#pragma unroll
    for (int n = 0; n < 2; ++n) acc[m][n] = (f32x16)0.0f;

  const int shA = wr << 4;     // byte (2wr+mb) -> shift shA + mb*8 (wave-uniform)
  const int shB = wc << 4;

  auto COMPUTE = [&](const char* base) {
    const char* bA = base + wr * 4096;
    const char* bB = base + 8192 + wc * 4096;
#pragma unroll
    for (int h = 0; h < 2; ++h) {
      const int ch = cR0 ^ (h << 4);
      i32x8v a8[2], b8[2];
#pragma unroll
      for (int mb = 0; mb < 2; ++mb) {
        i32x4v f = *(const i32x4v*)(bA + (mb * 32 + l31) * 64 + ch);
        a8[mb] = __builtin_shufflevector(f, f, 0, 1, 2, 3, -1, -1, -1, -1);
      }
#pragma unroll
      for (int nb = 0; nb < 2; ++nb) {
        i32x4v f = *(const i32x4v*)(bB + (nb * 32 + l31) * 64 + ch);
        b8[nb] = __builtin_shufflevector(f, f, 0, 1, 2, 3, -1, -1, -1, -1);
      }
      const int kb2 = 2 * h + lk;
      const int saw = *(const int*)(base + 16384 + kb2 * 128 + l31 * 4);
      const int sbw = *(const int*)(base + 16896 + kb2 * 128 + l31 * 4);
      const int sA0 = (saw >> shA) & 0xFF, sA1 = (saw >> (shA + 8)) & 0xFF;
      const int sB0 = (sbw >> shB) & 0xFF, sB1 = (sbw >> (shB + 8)) & 0xFF;
      MFMA4(0, 0, a8[0], b8[0], sA0, sB0)
      MFMA4(1, 0, a8[1], b8[0], sA1, sB0)
      MFMA4(0, 1, a8[0], b8[1], sA0, sB1)
      MFMA4(1, 1, a8[1], b8[1], sA1, sB1)
    }
  };

  char* const L0 = lds;
  char* const L1 = lds + 17408;

  STAGE(0, L0);

  for (int j = 0; j < (NTK >> 1); ++j) {
    // t = 2j: consume L0, stage t+1 -> L1
    STAGE(2 * j + 1, L1);
    VMCNT(5);          // retire t's 5 loads (issued a full iter ago)
    BAR();
    COMPUTE(L0);
    BAR();             // all waves done reading L0 before next STAGE overwrites
    // t = 2j+1: consume L1, stage t+2 -> L0
    STAGE(2 * j + 2, L0);
    VMCNT(5);
    BAR();
    COMPUTE(L1);
    BAR();
  }

  VMCNT(0);

  // epilogue: out = log(acc) + bias, nontemporal
  // 32x32 C/D layout: col = lane&31, row = (reg&3) + 8*(reg>>2) + 4*(lane>>5)
  const int col0 = bcol + wc * 64 + l31;
  const int row0 = brow + wr * 64 + lk * 4;
  const float bv0 = bias[col0], bv1 = bias[col0 + 32];
#pragma unroll
  for (int mb = 0; mb < 2; ++mb) {
#pragma unroll
    for (int rg = 0; rg < 16; ++rg) {
      const int row = row0 + mb * 32 + (rg & 3) + 8 * (rg >> 2);
      const size_t ro = (size_t)row * N + col0;
      __builtin_nontemporal_store(__logf(acc[mb][0][rg]) + bv0, &out[ro]);
      __builtin_nontemporal_store(__logf(acc[mb][1][rg]) + bv1, &out[ro + 32]);
    }
  }
}

extern "C" void kernel_launch(void* const* d_in, const int* in_sizes, int n_in,
                              void* d_out, int out_size, void* d_ws, size_t ws_size,
                              hipStream_t stream) {
  const float* inputs = (const float*)d_in[0];
  const float* w      = (const float*)d_in[1];
  const float* bias   = (const float*)d_in[2];
  float* out = (float*)d_out;

  const int O = in_sizes[2];                 // 2048
  const int D = in_sizes[1] / O;             // 2048
  const size_t MD = (size_t)in_sizes[0];     // M*D
  const int M = (int)(MD / (size_t)D);       // 16384

  unsigned char* ws  = (unsigned char*)d_ws;
  unsigned char* A4  = ws;                                   // 16 MB
  unsigned char* Bt4 = ws + MD / 2;                          // 2 MB
  unsigned char* SAt = Bt4 + (size_t)O * D / 2;              // 1 MB
  unsigned char* SBt = SAt + MD / 32;                        // 128 KB

  const int nthr = (int)((MD / 32 + 255) / 256);
  expcvt_a4_kernel<<<nthr, 256, 0, stream>>>(inputs, A4, SAt, M, D);

  dim3 tg(O / 32, D / 32);
  expcvt_wt4_kernel<<<tg, dim3(32, 8), 0, stream>>>(w, Bt4, SBt, D, O);

  dim3 grid((M / 128) * (O / 128));
  gemm_mx4d_kernel<<<grid, 256, 0, stream>>>(A4, Bt4, SAt, SBt, bias, out,
                                             M, O, D);
}